// Round 13
// baseline (1977.143 us; speedup 1.0000x reference)
//
#include <hip/hip_runtime.h>
#include <stdint.h>

#define V_  32000
#define E_  1024
#define H_  1024
#define B_  64
#define T_  128
#define MROWS (T_ * B_)        // 8192
#define NCB_ 250               // 32000 / 128 vocab chunks
#define NTG  32                // step groups of 4
#define NXW  1024              // xw items: 32 row-groups x 32 col-groups
#define ITEMS_PER_TG 258       // 8 proj + 250 logits
#define TOTAL_ITEMS (NXW + NTG * ITEMS_PER_TG)

typedef __bf16 bf16x8 __attribute__((ext_vector_type(8)));
typedef float  f32x4  __attribute__((ext_vector_type(4)));

__device__ __forceinline__ uint16_t f2b(float f) {
  uint32_t u = __builtin_bit_cast(uint32_t, f);
  return (uint16_t)((u + 0x7fffu + ((u >> 16) & 1u)) >> 16);
}
__device__ __forceinline__ float b2f(uint16_t h) {
  uint32_t u = ((uint32_t)h) << 16;
  return __builtin_bit_cast(float, u);
}
__device__ __forceinline__ float fsig_(float x) {
  return __builtin_amdgcn_rcpf(1.0f + __expf(-x));
}
__device__ __forceinline__ float ftanh_(float x) {
  return 2.0f * __builtin_amdgcn_rcpf(1.0f + __expf(-2.0f * x)) - 1.0f;
}

__device__ __forceinline__ void gload16(const uint16_t* g, uint16_t* l) {
  __builtin_amdgcn_global_load_lds(
      (const __attribute__((address_space(1))) uint32_t*)g,
      (__attribute__((address_space(3))) uint32_t*)l,
      16, 0, 0);
}

// ---------------- setup kernels ----------------

__global__ void k_cvt(const float* __restrict__ src, uint16_t* __restrict__ dst, int n4) {
  int i = blockIdx.x * blockDim.x + threadIdx.x;
  int st = gridDim.x * blockDim.x;
  for (; i < n4; i += st) {
    float4 v = ((const float4*)src)[i];
    ushort4 o;
    o.x = f2b(v.x); o.y = f2b(v.y); o.z = f2b(v.z); o.w = f2b(v.w);
    ((ushort4*)dst)[i] = o;
  }
}

__global__ void k_tcvt(const float* __restrict__ src, uint16_t* __restrict__ dst,
                       int R, int C, int dstStride, int dstOff) {
  __shared__ float tile[32][33];
  int c0 = blockIdx.x * 32, r0 = blockIdx.y * 32;
  int tx = threadIdx.x, ty = threadIdx.y;  // (32,8)
  for (int j = 0; j < 32; j += 8)
    tile[ty + j][tx] = src[(size_t)(r0 + ty + j) * C + c0 + tx];
  __syncthreads();
  for (int j = 0; j < 32; j += 8)
    dst[(size_t)(c0 + ty + j) * dstStride + dstOff + r0 + tx] = f2b(tile[tx][ty + j]);
}

__global__ void k_zero(uint4* p, int n) {
  int i = blockIdx.x * blockDim.x + threadIdx.x;
  int st = gridDim.x * blockDim.x;
  uint4 z = {0, 0, 0, 0};
  for (; i < n; i += st) p[i] = z;
}

// ---------------- MEGA kernel ----------------
// blk < 64 : persistent recurrence (R12 logic + xwDone gating + minStep relay).
// blk >= 64: work-stealing consumers. Queue order: 1024 xw items first
//            (xAll = emb[data] @ W_ih + b, sc1 writeback, xwDone counters),
//            then per-tg {8 proj, 250 logits} items.
//            proj-wait polls ONE minStep dword (de-contends flag lines).
__global__ __launch_bounds__(512) void k_mega(
    const int* __restrict__ data,
    const uint16_t* __restrict__ xAllR, uint16_t* __restrict__ xAllW,
    const uint16_t* __restrict__ Wcat,
    const float* __restrict__ bias, const float* __restrict__ mask,
    uint16_t* __restrict__ hAll, uint32_t* __restrict__ flags,
    const uint16_t* __restrict__ embB, const uint16_t* __restrict__ WrB,
    const float* __restrict__ br, const float* __restrict__ bd,
    uint16_t* __restrict__ outAll, float2* __restrict__ part,
    uint32_t* __restrict__ projDone, uint32_t* __restrict__ xwDone,
    uint32_t* __restrict__ minStep, uint32_t* __restrict__ workCtr)
{
  __shared__ alignas(16) char smem[151616];

  int tid = threadIdx.x;
  int blk = blockIdx.x;
  int w = tid >> 6, l = tid & 63, lr = l & 15, lg = l >> 4;

  if (blk < 64) {
    // ================= PRODUCER =================
    uint16_t* wh    = (uint16_t*)smem;                       // 128 KB
    uint16_t* xs0   = (uint16_t*)(smem + 131072);            // 8 KB
    uint16_t* xs1   = (uint16_t*)(smem + 139264);            // 8 KB
    uint16_t* hp0   = (uint16_t*)(smem + 147456);            // 2 KB
    uint16_t* hp1   = (uint16_t*)(smem + 149504);            // 2 KB
    uint32_t* ldsT  = (uint32_t*)(smem + 151552);            // step broadcast
    uint16_t* xsb[2] = {xs0, xs1};
    uint16_t* hpb[2] = {hp0, hp1};

    int u0 = blk * 16;

    for (int it = 0; it < 16; ++it) {
      int ch = it * 512 + tid;
      int c  = ch >> 7;
      int kb = (ch & 127) * 16;
      int gRow = (c & 3) * 1024 + u0 + (c >> 2);
      uint4 v = *(const uint4*)((const char*)Wcat + (size_t)gRow * 4096 + 2048 + kb);
      *(uint4*)((char*)wh + c * 2048 + (kb ^ ((c & 7) << 4))) = v;
    }

    int wm = w >> 1, wn = w & 1;
    int q = lr & 3;

    const char* wb0 = (const char*)wh + (size_t)(wn * 32 + lr) * 2048;
    const char* wb1 = (const char*)wh + (size_t)(wn * 32 + 16 + lr) * 2048;
    int xr = (lr & 7) << 4;

    int sRow = tid >> 3, sQ = (tid >> 1) & 3, sHalf = tid & 1;
    const uint16_t* xSrc = xAllR + (size_t)sRow * 4096 + sQ * 1024 + u0 + sHalf * 8;
    int xDstOff = sRow * 64 + sQ * 16 + sHalf * 8;
    int xoBase = (wm * 16 + lg * 4) * 64 + q * 16 + wn * 8 + (lr >> 2);

    float cR[2][4] = {}, hR[2][4] = {};

    if (tid == 0) *ldsT = 0;
    // gate on xw group 0 (uniform-dword poll)
    while (__hip_atomic_load(&xwDone[0], __ATOMIC_RELAXED, __HIP_MEMORY_SCOPE_AGENT) < 32u)
      __builtin_amdgcn_s_sleep(8);
    asm volatile("" ::: "memory");
    *(uint4*)&xsb[0][xDstOff] = *(const uint4*)xSrc;
    __syncthreads();

    int cur = 0;
    for (int t = 0; t < T_; ++t) {
      float xwv[2][4], mm_[4];
#pragma unroll
      for (int ni = 0; ni < 2; ++ni)
#pragma unroll
        for (int r = 0; r < 4; ++r)
          xwv[ni][r] = b2f(xsb[cur][xoBase + r * 64 + ni * 4]);
#pragma unroll
      for (int r = 0; r < 4; ++r)
        mm_[r] = mask[(t + 1) * B_ + wm * 16 + lg * 4 + r];

      if (t + 1 < T_) {
        if (((t + 1) & 3) == 0) {  // new xw group needed for t+1
          uint32_t g = (uint32_t)((t + 1) >> 2);
          while (__hip_atomic_load(&xwDone[g], __ATOMIC_RELAXED,
                                   __HIP_MEMORY_SCOPE_AGENT) < 32u)
            __builtin_amdgcn_s_sleep(8);
          asm volatile("" ::: "memory");
        }
        *(uint4*)&xsb[cur ^ 1][xDstOff] = *(const uint4*)(xSrc + (size_t)(t + 1) * B_ * 4096);
      }

      if (t > 0) {
        uint32_t tv = (uint32_t)t;
        if (w == 0) {
          while (!__all((int)(__hip_atomic_load(&flags[l], __ATOMIC_RELAXED,
                                                __HIP_MEMORY_SCOPE_AGENT) >= tv)))
            __builtin_amdgcn_s_sleep(1);
          __hip_atomic_store(ldsT, tv, __ATOMIC_RELEASE, __HIP_MEMORY_SCOPE_WORKGROUP);
          if (blk == 0 && l == 0)
            __hip_atomic_store(minStep, tv, __ATOMIC_RELAXED, __HIP_MEMORY_SCOPE_AGENT);
        } else {
          while (__hip_atomic_load(ldsT, __ATOMIC_ACQUIRE,
                                   __HIP_MEMORY_SCOPE_WORKGROUP) < tv)
            __builtin_amdgcn_s_sleep(1);
        }
        asm volatile("" ::: "memory");   // keep h loads below the poll
      }

      const uint16_t* aH = hAll + (size_t)t * (B_ * H_) + (size_t)(wm * 16 + lr) * H_ + lg * 8;

      f32x4 acc0 = {0.f, 0.f, 0.f, 0.f}, acc1 = {0.f, 0.f, 0.f, 0.f};
#pragma unroll 8
      for (int ks = 0; ks < 32; ++ks) {
        bf16x8 a = *(const bf16x8*)(aH + ks * 32);
        int ko = (ks * 64 + lg * 16) ^ xr;
        bf16x8 b0 = *(const bf16x8*)(wb0 + ko);
        bf16x8 b1 = *(const bf16x8*)(wb1 + ko);
        acc0 = __builtin_amdgcn_mfma_f32_16x16x32_bf16(a, b0, acc0, 0, 0, 0);
        acc1 = __builtin_amdgcn_mfma_f32_16x16x32_bf16(a, b1, acc1, 0, 0, 0);
      }

#pragma unroll
      for (int ni = 0; ni < 2; ++ni) {
        f32x4 accv = ni ? acc1 : acc0;
#pragma unroll
        for (int r = 0; r < 4; ++r) {
          float v0 = accv[r] + xwv[ni][r];
          float v1 = __shfl_xor(v0, 1, 64);
          float v2 = __shfl_xor(v0, 2, 64);
          float v3 = __shfl_xor(v0, 3, 64);
          float gi = (q == 0) ? v0 : (q == 1) ? v1 : (q == 2) ? v2 : v3;
          float gf = (q == 1) ? v0 : (q == 0) ? v1 : (q == 3) ? v2 : v3;
          float gg = (q == 2) ? v0 : (q == 3) ? v1 : (q == 0) ? v2 : v3;
          float go = (q == 3) ? v0 : (q == 2) ? v1 : (q == 1) ? v2 : v3;
          gi = fsig_(gi); gf = fsig_(gf); gg = ftanh_(gg); go = fsig_(go);
          float cn = gf * cR[ni][r] + gi * gg;
          float hn = go * ftanh_(cn);
          float mm = mm_[r];
          cR[ni][r] = mm * cn + (1.f - mm) * cR[ni][r];
          hR[ni][r] = mm * hn + (1.f - mm) * hR[ni][r];
          if (q == 0)
            hpb[cur][(wm * 16 + lg * 4 + r) * 16 + wn * 8 + ni * 4 + (lr >> 2)] = f2b(hR[ni][r]);
        }
      }

      __syncthreads();

      if (w == 0) {
        const unsigned long long* hp = (const unsigned long long*)hpb[cur];
        unsigned long long* hd =
            (unsigned long long*)(hAll + (size_t)(t + 1) * (B_ * H_) + (size_t)l * H_ + u0);
#pragma unroll
        for (int j = 0; j < 4; ++j)
          __hip_atomic_store(hd + j, hp[l * 4 + j],
                             __ATOMIC_RELAXED, __HIP_MEMORY_SCOPE_AGENT);
        asm volatile("s_waitcnt vmcnt(0)" ::: "memory");
        if (l == 0)
          __hip_atomic_store(&flags[blk], (uint32_t)(t + 1),
                             __ATOMIC_RELAXED, __HIP_MEMORY_SCOPE_AGENT);
      }
      cur ^= 1;
    }

    // epilogue: blk0 publishes minStep = T (all h(T) visible) for last proj tg
    if (blk == 0 && w == 0) {
      while (!__all((int)(__hip_atomic_load(&flags[l], __ATOMIC_RELAXED,
                                            __HIP_MEMORY_SCOPE_AGENT) >= (uint32_t)T_)))
        __builtin_amdgcn_s_sleep(1);
      if (l == 0)
        __hip_atomic_store(minStep, (uint32_t)T_, __ATOMIC_RELAXED, __HIP_MEMORY_SCOPE_AGENT);
    }
  } else {
    // ================= CONSUMER: unified 256x128xK1024 GEMM items ==========
    uint16_t* lA  = (uint16_t*)smem;                   // 32 KB  [256][64]
    uint16_t* lB  = (uint16_t*)(smem + 32768);         // 16 KB  [128][64]
    float2*   cm  = (float2*)(smem + 49152);           // 4 KB   [2][256]
    uint32_t* sId = (uint32_t*)(smem + 53248);

    int stRow = l >> 3;                                // 0..7
    int kswz  = ((l & 7) * 8) ^ ((stRow & 7) << 3);
    int wr = w >> 1;                                   // 0..3 (64-row quarter)
    int wc = w & 1;                                    // 0..1 (64-col half)

    for (;;) {
      __syncthreads();
      if (tid == 0)
        *sId = __hip_atomic_fetch_add(workCtr, 1u, __ATOMIC_RELAXED, __HIP_MEMORY_SCOPE_AGENT);
      __syncthreads();
      uint32_t id = *sId;
      if (id >= TOTAL_ITEMS) break;

      int itemType;          // 0=xw, 1=proj, 2=logits
      int tg = 0, sub = 0, rgx = 0, cgx = 0;
      if (id < NXW) {
        itemType = 0; rgx = (int)(id >> 5); cgx = (int)(id & 31);
      } else {
        int id2 = (int)(id - NXW);
        tg = id2 / ITEMS_PER_TG; sub = id2 % ITEMS_PER_TG;
        itemType = (sub < 8) ? 1 : 2;
      }
      int t0 = tg * 4;

      const uint16_t* aSrc[4];
      const uint16_t* bS;
      const float* biasp;
      int bStride;
      if (itemType == 0) {
        // xw: A = emb[data[rows]], B = Wcat emb-half (row stride 2048)
#pragma unroll
        for (int cc = 0; cc < 4; ++cc) {
          int row = rgx * 256 + w * 32 + cc * 8 + stRow;
          aSrc[cc] = embB + (size_t)data[row] * 1024 + kswz;
        }
        bS = Wcat + (size_t)(cgx * 128 + w * 16 + stRow) * 2048 + kswz;
        biasp = bias + cgx * 128;
        bStride = 2048;
      } else if (itemType == 1) {
        while (__hip_atomic_load(minStep, __ATOMIC_RELAXED,
                                 __HIP_MEMORY_SCOPE_AGENT) < (uint32_t)(t0 + 4))
          __builtin_amdgcn_s_sleep(16);
        asm volatile("" ::: "memory");
        const uint16_t* Abase = hAll + (size_t)(t0 + 1) * (B_ * H_);
#pragma unroll
        for (int cc = 0; cc < 4; ++cc)
          aSrc[cc] = Abase + (size_t)(w * 32 + cc * 8 + stRow) * 1024 + kswz;
        bS = WrB + (size_t)(sub * 128 + w * 16 + stRow) * 1024 + kswz;
        biasp = br + sub * 128;
        bStride = 1024;
      } else {
        while (__hip_atomic_load(&projDone[tg], __ATOMIC_RELAXED,
                                 __HIP_MEMORY_SCOPE_AGENT) < 8u)
          __builtin_amdgcn_s_sleep(16);
        asm volatile("" ::: "memory");
        const uint16_t* Abase = outAll + (size_t)t0 * B_ * 1024;
#pragma unroll
        for (int cc = 0; cc < 4; ++cc)
          aSrc[cc] = Abase + (size_t)(w * 32 + cc * 8 + stRow) * 1024 + kswz;
        bS = embB + (size_t)((sub - 8) * 128 + w * 16 + stRow) * 1024 + kswz;
        biasp = bd + (sub - 8) * 128;
        bStride = 1024;
      }

      f32x4 acc[4][4] = {};
      for (int kt = 0; kt < 1024; kt += 64) {
#pragma unroll
        for (int cc = 0; cc < 4; ++cc)
          gload16(aSrc[cc] + (size_t)cc * 0 + (size_t)kt, &lA[(w * 4 + cc) * 512]);
#pragma unroll
        for (int cc = 0; cc < 2; ++cc)
          gload16(bS + (size_t)cc * 8 * bStride + kt, &lB[(w * 2 + cc) * 512]);
        __syncthreads();
#pragma unroll
        for (int ksub = 0; ksub < 2; ++ksub) {
          int ke = ksub * 32 + lg * 8;
          bf16x8 af[4], bfr[4];
#pragma unroll
          for (int mi = 0; mi < 4; ++mi) {
            int row = wr * 64 + mi * 16 + lr;
            af[mi] = *(const bf16x8*)&lA[row * 64 + (ke ^ ((row & 7) << 3))];
          }
#pragma unroll
          for (int ni = 0; ni < 4; ++ni) {
            int row = wc * 64 + ni * 16 + lr;
            bfr[ni] = *(const bf16x8*)&lB[row * 64 + (ke ^ ((row & 7) << 3))];
          }
#pragma unroll
          for (int mi = 0; mi < 4; ++mi)
#pragma unroll
            for (int ni = 0; ni < 4; ++ni)
              acc[mi][ni] = __builtin_amdgcn_mfma_f32_16x16x32_bf16(af[mi], bfr[ni], acc[mi][ni], 0, 0, 0);
        }
        __syncthreads();
      }

      float bv[4];
#pragma unroll
      for (int ni = 0; ni < 4; ++ni) bv[ni] = biasp[wc * 64 + ni * 16 + lr];

      if (itemType == 0) {
        // writeback 256x128 to xAll via LDS bounce + sc1 stores
        int n0 = cgx * 128;
        uint16_t* opack = lA;          // 16 KB [64][128]
#pragma unroll
        for (int chunk = 0; chunk < 4; ++chunk) {
          if (wr == chunk) {
#pragma unroll
            for (int mi = 0; mi < 4; ++mi)
#pragma unroll
              for (int ni = 0; ni < 4; ++ni)
#pragma unroll
                for (int r = 0; r < 4; ++r)
                  opack[(mi * 16 + lg * 4 + r) * 128 + wc * 64 + ni * 16 + lr]
                    = f2b(acc[mi][ni][r] + bv[ni]);
          }
          __syncthreads();
          const unsigned long long* op = (const unsigned long long*)opack;
#pragma unroll
          for (int j = 0; j < 4; ++j) {
            int g2 = j * 512 + tid;
            int row = g2 >> 5, seg = g2 & 31;
            unsigned long long* od =
                (unsigned long long*)(xAllW + (size_t)(rgx * 256 + chunk * 64 + row) * 4096 + n0) + seg;
            __hip_atomic_store(od, op[g2], __ATOMIC_RELAXED, __HIP_MEMORY_SCOPE_AGENT);
          }
          __syncthreads();
        }
        asm volatile("s_waitcnt vmcnt(0)" ::: "memory");
        __syncthreads();
        if (tid == 0)
          __hip_atomic_fetch_add(&xwDone[rgx], 1u, __ATOMIC_RELAXED, __HIP_MEMORY_SCOPE_AGENT);
      } else if (itemType == 1) {
        int e0 = sub * 128;
        uint16_t* opack = lA;          // 16 KB [64][128]
#pragma unroll
        for (int chunk = 0; chunk < 4; ++chunk) {
          if (wr == chunk) {
#pragma unroll
            for (int mi = 0; mi < 4; ++mi)
#pragma unroll
              for (int ni = 0; ni < 4; ++ni)
#pragma unroll
                for (int r = 0; r < 4; ++r)
                  opack[(mi * 16 + lg * 4 + r) * 128 + wc * 64 + ni * 16 + lr]
                    = f2b(acc[mi][ni][r] + bv[ni]);
          }
          __syncthreads();
          const unsigned long long* op = (const unsigned long long*)opack;
#pragma unroll
          for (int j = 0; j < 4; ++j) {
            int g2 = j * 512 + tid;
            int row = g2 >> 5, seg = g2 & 31;
            unsigned long long* od =
                (unsigned long long*)(outAll + ((size_t)(t0 + chunk) * B_ + row) * 1024 + e0) + seg;
            __hip_atomic_store(od, op[g2], __ATOMIC_RELAXED, __HIP_MEMORY_SCOPE_AGENT);
          }
          __syncthreads();
        }
        asm volatile("s_waitcnt vmcnt(0)" ::: "memory");
        __syncthreads();
        if (tid == 0)
          __hip_atomic_fetch_add(&projDone[tg], 1u, __ATOMIC_RELAXED, __HIP_MEMORY_SCOPE_AGENT);
      } else {
        int nc = sub - 8;
#pragma unroll
        for (int mi = 0; mi < 4; ++mi) {
#pragma unroll
          for (int r = 0; r < 4; ++r) {
            float mx = -1e30f;
#pragma unroll
            for (int ni = 0; ni < 4; ++ni) { acc[mi][ni][r] += bv[ni]; mx = fmaxf(mx, acc[mi][ni][r]); }
#pragma unroll
            for (int d = 1; d < 16; d <<= 1) mx = fmaxf(mx, __shfl_xor(mx, d, 64));
            float s = 0.f;
#pragma unroll
            for (int ni = 0; ni < 4; ++ni) s += expf(acc[mi][ni][r] - mx);
#pragma unroll
            for (int d = 1; d < 16; d <<= 1) s += __shfl_xor(s, d, 64);
            if (lr == 0) cm[wc * 256 + wr * 64 + mi * 16 + lg * 4 + r] = make_float2(mx, s);
          }
        }
        __syncthreads();
        if (tid < 256) {
          float2 p0 = cm[tid], p1 = cm[256 + tid];
          float M = fmaxf(p0.x, p1.x);
          float S = p0.y * expf(p0.x - M) + p1.y * expf(p1.x - M);
          part[(size_t)nc * MROWS + (size_t)t0 * B_ + tid] = make_float2(M, S);
        }
      }
    }
  }
}

// ---------------- target logits ----------------
__global__ __launch_bounds__(256) void k_tgt(
    const uint16_t* __restrict__ outAll, const uint16_t* __restrict__ embB,
    const float* __restrict__ bd, const int* __restrict__ data, float* __restrict__ tgt)
{
  int w = threadIdx.x >> 6, l = threadIdx.x & 63;
  int row = blockIdx.x * 4 + w;
  int t = row >> 6, b = row & 63;
  int ty = data[(t + 1) * B_ + b];
  const uint16_t* a = outAll + (size_t)row * E_;
  const uint16_t* e = embB + (size_t)ty * E_;
  float s = 0.f;
#pragma unroll
  for (int i0 = 0; i0 < 2; ++i0) {
    int i = (l + i0 * 64) * 8;
    bf16x8 av = *(const bf16x8*)(a + i);
    bf16x8 ev = *(const bf16x8*)(e + i);
#pragma unroll
    for (int j = 0; j < 8; ++j) s += (float)av[j] * (float)ev[j];
  }
#pragma unroll
  for (int d = 1; d < 64; d <<= 1) s += __shfl_xor(s, d, 64);
  if (l == 0) tgt[row] = s + bd[ty];
}

// ---------------- LSE over 250 chunks + NLL per row ----------------
__global__ __launch_bounds__(256) void k_lse(
    const float2* __restrict__ part, const float* __restrict__ tgt,
    const float* __restrict__ mask, float* __restrict__ rowNll)
{
  int w = threadIdx.x >> 6, l = threadIdx.x & 63;
  int row = blockIdx.x * 4 + w;
  float m = -1e30f, s = 0.f;
  for (int cc = l; cc < NCB_; cc += 64) {
    float2 v = part[(size_t)cc * MROWS + row];
    float M = fmaxf(m, v.x);
    s = s * expf(m - M) + v.y * expf(v.x - M);
    m = M;
  }
#pragma unroll
  for (int d = 1; d < 64; d <<= 1) {
    float om = __shfl_xor(m, d, 64);
    float os = __shfl_xor(s, d, 64);
    float M = fmaxf(m, om);
    s = s * expf(m - M) + os * expf(om - M);
    m = M;
  }
  if (l == 0) {
    int t = row >> 6, b = row & 63;
    float nll = (m + logf(s)) - tgt[row];
    rowNll[row] = nll * mask[(t + 1) * B_ + b];
  }
}

__global__ void k_final2(const float* __restrict__ rowNll, float* __restrict__ out) {
  __shared__ float red[256];
  float s = 0.f;
  for (int i = threadIdx.x; i < MROWS; i += 256) s += rowNll[i];
  red[threadIdx.x] = s;
  __syncthreads();
  for (int st = 128; st > 0; st >>= 1) {
    if ((int)threadIdx.x < st) red[threadIdx.x] += red[threadIdx.x + st];
    __syncthreads();
  }
  if (threadIdx.x == 0) out[0] = red[0] / (float)(B_ * B_);
}

// ---------------- host ----------------
extern "C" void kernel_launch(void* const* d_in, const int* in_sizes, int n_in,
                              void* d_out, int out_size, void* d_ws, size_t ws_size,
                              hipStream_t stream)
{
  const int*   data = (const int*)  d_in[0];
  const float* mask = (const float*)d_in[1];
  const float* emb  = (const float*)d_in[2];
  const float* W_ih = (const float*)d_in[3];
  const float* W_hh = (const float*)d_in[4];
  const float* bias = (const float*)d_in[5];
  const float* Wr   = (const float*)d_in[6];
  const float* br   = (const float*)d_in[7];
  const float* bd   = (const float*)d_in[8];
  (void)in_sizes; (void)n_in; (void)out_size; (void)ws_size;

  char* ws = (char*)d_ws;
  size_t off = 0;
  auto alloc = [&](size_t bytes) -> char* {
    char* p = ws + off;
    off += (bytes + 255) & ~(size_t)255;
    return p;
  };
  uint16_t* embB   = (uint16_t*)alloc((size_t)V_ * E_ * 2);            // 65.5 MB
  uint16_t* Wcat   = (uint16_t*)alloc((size_t)4 * H_ * 2048 * 2);      // 16.8 MB
  uint16_t* WrB    = (uint16_t*)alloc((size_t)E_ * H_ * 2);            // 2.1 MB
  uint16_t* hAll   = (uint16_t*)alloc((size_t)(T_ + 1) * B_ * H_ * 2); // 16.9 MB
  uint16_t* xAll   = (uint16_t*)alloc((size_t)MROWS * 4096 * 2);       // 67.1 MB
  uint16_t* outAll = (uint16_t*)alloc((size_t)MROWS * E_ * 2);         // 16.8 MB
  float2*   part   = (float2*)  alloc((size_t)NCB_ * MROWS * 8);       // 16.4 MB
  float*    tgt    = (float*)   alloc((size_t)MROWS * 4);
  float*    rowNll = (float*)   alloc((size_t)MROWS * 4);
  uint32_t* syncb  = (uint32_t*)alloc(4096);
  uint32_t* flags    = syncb;          // 64 dwords
  uint32_t* projDone = syncb + 128;    // 32 dwords (per tg)
  uint32_t* xwDone   = syncb + 192;    // 32 dwords (per row-group)
  uint32_t* workCtr  = syncb + 512;    // 1 dword
  uint32_t* minStep  = syncb + 576;    // 1 dword (own line)

  // one-time conversions
  k_cvt <<<2048, 256, 0, stream>>>(emb, embB, V_ * E_ / 4);
  k_cvt <<<256,  256, 0, stream>>>(Wr, WrB, E_ * H_ / 4);
  k_tcvt<<<dim3(4 * H_ / 32, E_ / 32), dim3(32, 8), 0, stream>>>(W_ih, Wcat, E_, 4 * H_, 2048, 0);
  k_tcvt<<<dim3(4 * H_ / 32, H_ / 32), dim3(32, 8), 0, stream>>>(W_hh, Wcat, H_, 4 * H_, 2048, 1024);
  k_zero<<<32, 256, 0, stream>>>((uint4*)hAll, B_ * H_ * 2 / 16);
  k_zero<<<1, 256, 0, stream>>>((uint4*)syncb, 4096 / 16);

  // fused xW + recurrence + projection + logits
  k_mega<<<256, 512, 0, stream>>>(data, xAll, xAll, Wcat, bias, mask, hAll, flags,
                                  embB, WrB, br, bd, outAll, part,
                                  projDone, xwDone, minStep, workCtr);

  k_tgt   <<<MROWS / 4, 256, 0, stream>>>(outAll, embB, bd, data, tgt);
  k_lse   <<<MROWS / 4, 256, 0, stream>>>(part, tgt, mask, rowNll);
  k_final2<<<1, 256, 0, stream>>>(rowNll, (float*)d_out);
}

// Round 14
// 1954.202 us; speedup vs baseline: 1.0117x; 1.0117x over previous
//
#include <hip/hip_runtime.h>
#include <stdint.h>

#define V_  32000
#define E_  1024
#define H_  1024
#define B_  64
#define T_  128
#define MROWS (T_ * B_)        // 8192
#define NCB_ 250               // 32000 / 128 vocab chunks
#define NTG  32                // step groups of 4
#define ITEMS_PER_TG 258       // 8 proj + 250 logits
#define TOTAL_ITEMS (NTG * ITEMS_PER_TG)

typedef __bf16 bf16x8 __attribute__((ext_vector_type(8)));
typedef float  f32x4  __attribute__((ext_vector_type(4)));

__device__ __forceinline__ uint16_t f2b(float f) {
  uint32_t u = __builtin_bit_cast(uint32_t, f);
  return (uint16_t)((u + 0x7fffu + ((u >> 16) & 1u)) >> 16);
}
__device__ __forceinline__ float b2f(uint16_t h) {
  uint32_t u = ((uint32_t)h) << 16;
  return __builtin_bit_cast(float, u);
}
__device__ __forceinline__ float fsig_(float x) {
  return __builtin_amdgcn_rcpf(1.0f + __expf(-x));
}
__device__ __forceinline__ float ftanh_(float x) {
  return 2.0f * __builtin_amdgcn_rcpf(1.0f + __expf(-2.0f * x)) - 1.0f;
}

__device__ __forceinline__ void gload16(const uint16_t* g, uint16_t* l) {
  __builtin_amdgcn_global_load_lds(
      (const __attribute__((address_space(1))) uint32_t*)g,
      (__attribute__((address_space(3))) uint32_t*)l,
      16, 0, 0);
}

// ---------------- setup kernels ----------------

__global__ void k_cvt(const float* __restrict__ src, uint16_t* __restrict__ dst, int n4) {
  int i = blockIdx.x * blockDim.x + threadIdx.x;
  int st = gridDim.x * blockDim.x;
  for (; i < n4; i += st) {
    float4 v = ((const float4*)src)[i];
    ushort4 o;
    o.x = f2b(v.x); o.y = f2b(v.y); o.z = f2b(v.z); o.w = f2b(v.w);
    ((ushort4*)dst)[i] = o;
  }
}

__global__ void k_tcvt(const float* __restrict__ src, uint16_t* __restrict__ dst,
                       int R, int C, int dstStride, int dstOff) {
  __shared__ float tile[32][33];
  int c0 = blockIdx.x * 32, r0 = blockIdx.y * 32;
  int tx = threadIdx.x, ty = threadIdx.y;  // (32,8)
  for (int j = 0; j < 32; j += 8)
    tile[ty + j][tx] = src[(size_t)(r0 + ty + j) * C + c0 + tx];
  __syncthreads();
  for (int j = 0; j < 32; j += 8)
    dst[(size_t)(c0 + ty + j) * dstStride + dstOff + r0 + tx] = f2b(tile[tx][ty + j]);
}

__global__ void k_zero(uint4* p, int n) {
  int i = blockIdx.x * blockDim.x + threadIdx.x;
  int st = gridDim.x * blockDim.x;
  uint4 z = {0, 0, 0, 0};
  for (; i < n; i += st) p[i] = z;
}

// ---------------- xW precompute: xAll[r][n] = emb[data[r]] . Wih[n] + b[n] ----------------
__global__ __launch_bounds__(256) void k_xw(
    const int* __restrict__ data, const uint16_t* __restrict__ embB,
    const uint16_t* __restrict__ Wcat,
    const float* __restrict__ bias, uint16_t* __restrict__ xAll)
{
  __shared__ uint16_t lA[128 * 64];
  __shared__ uint16_t lB[128 * 64];

  int tid = threadIdx.x;
  int w = tid >> 6, l = tid & 63, lr = l & 15, lg = l >> 4;
  int wr = w >> 1, wc = w & 1;
  int m0 = blockIdx.x * 128;
  int n0 = blockIdx.y * 128;

  int stRow = l >> 3;
  int kswz  = ((l & 7) * 8) ^ ((stRow & 7) << 3);
  const uint16_t* aSrc[4];
  const uint16_t* bSrc[4];
#pragma unroll
  for (int cc = 0; cc < 4; ++cc) {
    int tok = data[m0 + w * 32 + cc * 8 + stRow];
    aSrc[cc] = embB + (size_t)tok * 1024 + kswz;
    bSrc[cc] = Wcat + (size_t)(n0 + w * 32 + cc * 8 + stRow) * 2048 + kswz;
  }

  f32x4 acc[4][4] = {};

  for (int kt = 0; kt < 1024; kt += 64) {
#pragma unroll
    for (int cc = 0; cc < 4; ++cc) {
      gload16(aSrc[cc] + kt, &lA[(w * 4 + cc) * 512]);
      gload16(bSrc[cc] + kt, &lB[(w * 4 + cc) * 512]);
    }
    __syncthreads();
#pragma unroll
    for (int ksub = 0; ksub < 2; ++ksub) {
      bf16x8 af[4], bfr[4];
      int ke = ksub * 32 + lg * 8;
#pragma unroll
      for (int mi = 0; mi < 4; ++mi) {
        int row = wr * 64 + mi * 16 + lr;
        af[mi] = *(const bf16x8*)&lA[row * 64 + (ke ^ ((row & 7) << 3))];
      }
#pragma unroll
      for (int ni = 0; ni < 4; ++ni) {
        int row = wc * 64 + ni * 16 + lr;
        bfr[ni] = *(const bf16x8*)&lB[row * 64 + (ke ^ ((row & 7) << 3))];
      }
#pragma unroll
      for (int mi = 0; mi < 4; ++mi)
#pragma unroll
        for (int ni = 0; ni < 4; ++ni)
          acc[mi][ni] = __builtin_amdgcn_mfma_f32_16x16x32_bf16(af[mi], bfr[ni], acc[mi][ni], 0, 0, 0);
    }
    __syncthreads();
  }

  float bv[4];
#pragma unroll
  for (int ni = 0; ni < 4; ++ni) bv[ni] = bias[n0 + wc * 64 + ni * 16 + lr];
#pragma unroll
  for (int mi = 0; mi < 4; ++mi)
#pragma unroll
    for (int ni = 0; ni < 4; ++ni) {
      int row = wr * 64 + mi * 16 + lg * 4;
      int col = n0 + wc * 64 + ni * 16 + lr;
#pragma unroll
      for (int r = 0; r < 4; ++r)
        xAll[(size_t)(m0 + row + r) * 4096 + col] = f2b(acc[mi][ni][r] + bv[ni]);
    }
}

// ---------------- MEGA kernel: producers (recurrence) + consumers (proj+logits) ----
// blk < 64 : persistent recurrence (R12 logic: wave0 polls global flags,
//            waves 1-7 spin on LDS). NEW: blk0/wave0/lane0 republishes the
//            detected step as ONE minStep dword (own cache line).
// blk >= 64: consumers; proj-wait polls the single minStep dword instead of
//            the 64 flag words (de-contends the producers' flag lines).
__global__ __launch_bounds__(512) void k_mega(
    const uint16_t* __restrict__ xAll, const uint16_t* __restrict__ Wcat,
    const float* __restrict__ mask, uint16_t* __restrict__ hAll,
    uint32_t* __restrict__ flags,
    const uint16_t* __restrict__ embB, const uint16_t* __restrict__ WrB,
    const float* __restrict__ br, const float* __restrict__ bd,
    uint16_t* __restrict__ outAll, float2* __restrict__ part,
    uint32_t* __restrict__ projDone, uint32_t* __restrict__ minStep,
    uint32_t* __restrict__ workCtr)
{
  __shared__ alignas(16) char smem[151616];

  int tid = threadIdx.x;
  int blk = blockIdx.x;
  int w = tid >> 6, l = tid & 63, lr = l & 15, lg = l >> 4;

  if (blk < 64) {
    // ================= PRODUCER (R12 + minStep relay) =================
    uint16_t* wh    = (uint16_t*)smem;                       // 128 KB
    uint16_t* xs0   = (uint16_t*)(smem + 131072);            // 8 KB
    uint16_t* xs1   = (uint16_t*)(smem + 139264);            // 8 KB
    uint16_t* hp0   = (uint16_t*)(smem + 147456);            // 2 KB
    uint16_t* hp1   = (uint16_t*)(smem + 149504);            // 2 KB
    uint32_t* ldsT  = (uint32_t*)(smem + 151552);            // 4 B step broadcast
    uint16_t* xsb[2] = {xs0, xs1};
    uint16_t* hpb[2] = {hp0, hp1};

    int u0 = blk * 16;

    for (int it = 0; it < 16; ++it) {
      int ch = it * 512 + tid;
      int c  = ch >> 7;
      int kb = (ch & 127) * 16;
      int gRow = (c & 3) * 1024 + u0 + (c >> 2);
      uint4 v = *(const uint4*)((const char*)Wcat + (size_t)gRow * 4096 + 2048 + kb);
      *(uint4*)((char*)wh + c * 2048 + (kb ^ ((c & 7) << 4))) = v;
    }

    int wm = w >> 1, wn = w & 1;
    int q = lr & 3;

    const char* wb0 = (const char*)wh + (size_t)(wn * 32 + lr) * 2048;
    const char* wb1 = (const char*)wh + (size_t)(wn * 32 + 16 + lr) * 2048;
    int xr = (lr & 7) << 4;

    int sRow = tid >> 3, sQ = (tid >> 1) & 3, sHalf = tid & 1;
    const uint16_t* xSrc = xAll + (size_t)sRow * 4096 + sQ * 1024 + u0 + sHalf * 8;
    int xDstOff = sRow * 64 + sQ * 16 + sHalf * 8;
    int xoBase = (wm * 16 + lg * 4) * 64 + q * 16 + wn * 8 + (lr >> 2);

    float cR[2][4] = {}, hR[2][4] = {};

    if (tid == 0) *ldsT = 0;
    *(uint4*)&xsb[0][xDstOff] = *(const uint4*)xSrc;
    __syncthreads();

    int cur = 0;
    for (int t = 0; t < T_; ++t) {
      float xwv[2][4], mm_[4];
#pragma unroll
      for (int ni = 0; ni < 2; ++ni)
#pragma unroll
        for (int r = 0; r < 4; ++r)
          xwv[ni][r] = b2f(xsb[cur][xoBase + r * 64 + ni * 4]);
#pragma unroll
      for (int r = 0; r < 4; ++r)
        mm_[r] = mask[(t + 1) * B_ + wm * 16 + lg * 4 + r];

      if (t + 1 < T_)
        *(uint4*)&xsb[cur ^ 1][xDstOff] = *(const uint4*)(xSrc + (size_t)(t + 1) * B_ * 4096);

      if (t > 0) {
        uint32_t tv = (uint32_t)t;
        if (w == 0) {
          while (!__all((int)(__hip_atomic_load(&flags[l], __ATOMIC_RELAXED,
                                                __HIP_MEMORY_SCOPE_AGENT) >= tv)))
            __builtin_amdgcn_s_sleep(1);
          __hip_atomic_store(ldsT, tv, __ATOMIC_RELEASE, __HIP_MEMORY_SCOPE_WORKGROUP);
          if (blk == 0 && l == 0)
            __hip_atomic_store(minStep, tv, __ATOMIC_RELAXED, __HIP_MEMORY_SCOPE_AGENT);
        } else {
          while (__hip_atomic_load(ldsT, __ATOMIC_ACQUIRE,
                                   __HIP_MEMORY_SCOPE_WORKGROUP) < tv)
            __builtin_amdgcn_s_sleep(1);
        }
        asm volatile("" ::: "memory");   // keep h loads below the poll
      }

      const uint16_t* aH = hAll + (size_t)t * (B_ * H_) + (size_t)(wm * 16 + lr) * H_ + lg * 8;

      f32x4 acc0 = {0.f, 0.f, 0.f, 0.f}, acc1 = {0.f, 0.f, 0.f, 0.f};
#pragma unroll 8
      for (int ks = 0; ks < 32; ++ks) {
        bf16x8 a = *(const bf16x8*)(aH + ks * 32);
        int ko = (ks * 64 + lg * 16) ^ xr;
        bf16x8 b0 = *(const bf16x8*)(wb0 + ko);
        bf16x8 b1 = *(const bf16x8*)(wb1 + ko);
        acc0 = __builtin_amdgcn_mfma_f32_16x16x32_bf16(a, b0, acc0, 0, 0, 0);
        acc1 = __builtin_amdgcn_mfma_f32_16x16x32_bf16(a, b1, acc1, 0, 0, 0);
      }

#pragma unroll
      for (int ni = 0; ni < 2; ++ni) {
        f32x4 accv = ni ? acc1 : acc0;
#pragma unroll
        for (int r = 0; r < 4; ++r) {
          float v0 = accv[r] + xwv[ni][r];
          float v1 = __shfl_xor(v0, 1, 64);
          float v2 = __shfl_xor(v0, 2, 64);
          float v3 = __shfl_xor(v0, 3, 64);
          float gi = (q == 0) ? v0 : (q == 1) ? v1 : (q == 2) ? v2 : v3;
          float gf = (q == 1) ? v0 : (q == 0) ? v1 : (q == 3) ? v2 : v3;
          float gg = (q == 2) ? v0 : (q == 3) ? v1 : (q == 0) ? v2 : v3;
          float go = (q == 3) ? v0 : (q == 2) ? v1 : (q == 1) ? v2 : v3;
          gi = fsig_(gi); gf = fsig_(gf); gg = ftanh_(gg); go = fsig_(go);
          float cn = gf * cR[ni][r] + gi * gg;
          float hn = go * ftanh_(cn);
          float mm = mm_[r];
          cR[ni][r] = mm * cn + (1.f - mm) * cR[ni][r];
          hR[ni][r] = mm * hn + (1.f - mm) * hR[ni][r];
          if (q == 0)
            hpb[cur][(wm * 16 + lg * 4 + r) * 16 + wn * 8 + ni * 4 + (lr >> 2)] = f2b(hR[ni][r]);
        }
      }

      __syncthreads();

      if (w == 0) {
        const unsigned long long* hp = (const unsigned long long*)hpb[cur];
        unsigned long long* hd =
            (unsigned long long*)(hAll + (size_t)(t + 1) * (B_ * H_) + (size_t)l * H_ + u0);
#pragma unroll
        for (int j = 0; j < 4; ++j)
          __hip_atomic_store(hd + j, hp[l * 4 + j],
                             __ATOMIC_RELAXED, __HIP_MEMORY_SCOPE_AGENT);
        asm volatile("s_waitcnt vmcnt(0)" ::: "memory");
        if (l == 0)
          __hip_atomic_store(&flags[blk], (uint32_t)(t + 1),
                             __ATOMIC_RELAXED, __HIP_MEMORY_SCOPE_AGENT);
      }
      cur ^= 1;
    }

    // epilogue: blk0 publishes minStep = T once all h(T) are visible
    if (blk == 0 && w == 0) {
      while (!__all((int)(__hip_atomic_load(&flags[l], __ATOMIC_RELAXED,
                                            __HIP_MEMORY_SCOPE_AGENT) >= (uint32_t)T_)))
        __builtin_amdgcn_s_sleep(1);
      if (l == 0)
        __hip_atomic_store(minStep, (uint32_t)T_, __ATOMIC_RELAXED, __HIP_MEMORY_SCOPE_AGENT);
    }
  } else {
    // ================= CONSUMER: unified 256x128xK1024 GEMM items ==========
    uint16_t* lA  = (uint16_t*)smem;                   // 32 KB  [256][64]
    uint16_t* lB  = (uint16_t*)(smem + 32768);         // 16 KB  [128][64]
    float2*   cm  = (float2*)(smem + 49152);           // 4 KB   [2][256]
    uint32_t* sId = (uint32_t*)(smem + 53248);

    int stRow = l >> 3;                                // 0..7
    int kswz  = ((l & 7) * 8) ^ ((stRow & 7) << 3);
    int wr = w >> 1;                                   // 0..3 (64-row quarter)
    int wc = w & 1;                                    // 0..1 (64-col half)

    for (;;) {
      __syncthreads();
      if (tid == 0)
        *sId = __hip_atomic_fetch_add(workCtr, 1u, __ATOMIC_RELAXED, __HIP_MEMORY_SCOPE_AGENT);
      __syncthreads();
      uint32_t id = *sId;
      if (id >= TOTAL_ITEMS) break;
      int tg = (int)(id / ITEMS_PER_TG), sub = (int)(id % ITEMS_PER_TG);
      int t0 = tg * 4;
      bool isProj = (sub < 8);

      const uint16_t* Abase;
      const uint16_t* Bbase;
      const float* biasp;
      if (isProj) {
        // single uniform-dword poll (minStep relay)
        while (__hip_atomic_load(minStep, __ATOMIC_RELAXED,
                                 __HIP_MEMORY_SCOPE_AGENT) < (uint32_t)(t0 + 4))
          __builtin_amdgcn_s_sleep(16);
        asm volatile("" ::: "memory");
        Abase = hAll + (size_t)(t0 + 1) * (B_ * H_);
        Bbase = WrB + (size_t)(sub * 128) * 1024;
        biasp = br + sub * 128;
      } else {
        while (__hip_atomic_load(&projDone[tg], __ATOMIC_RELAXED,
                                 __HIP_MEMORY_SCOPE_AGENT) < 8u)
          __builtin_amdgcn_s_sleep(16);
        asm volatile("" ::: "memory");
        Abase = outAll + (size_t)t0 * B_ * 1024;
        Bbase = embB + (size_t)(sub - 8) * 128 * 1024;
        biasp = bd + (sub - 8) * 128;
      }

      const uint16_t* aS = Abase + (size_t)(w * 32 + stRow) * 1024 + kswz;
      const uint16_t* bS = Bbase + (size_t)(w * 16 + stRow) * 1024 + kswz;

      f32x4 acc[4][4] = {};
      for (int kt = 0; kt < 1024; kt += 64) {
#pragma unroll
        for (int cc = 0; cc < 4; ++cc)
          gload16(aS + (size_t)cc * 8 * 1024 + kt, &lA[(w * 4 + cc) * 512]);
#pragma unroll
        for (int cc = 0; cc < 2; ++cc)
          gload16(bS + (size_t)cc * 8 * 1024 + kt, &lB[(w * 2 + cc) * 512]);
        __syncthreads();
#pragma unroll
        for (int ksub = 0; ksub < 2; ++ksub) {
          int ke = ksub * 32 + lg * 8;
          bf16x8 af[4], bfr[4];
#pragma unroll
          for (int mi = 0; mi < 4; ++mi) {
            int row = wr * 64 + mi * 16 + lr;
            af[mi] = *(const bf16x8*)&lA[row * 64 + (ke ^ ((row & 7) << 3))];
          }
#pragma unroll
          for (int ni = 0; ni < 4; ++ni) {
            int row = wc * 64 + ni * 16 + lr;
            bfr[ni] = *(const bf16x8*)&lB[row * 64 + (ke ^ ((row & 7) << 3))];
          }
#pragma unroll
          for (int mi = 0; mi < 4; ++mi)
#pragma unroll
            for (int ni = 0; ni < 4; ++ni)
              acc[mi][ni] = __builtin_amdgcn_mfma_f32_16x16x32_bf16(af[mi], bfr[ni], acc[mi][ni], 0, 0, 0);
        }
        __syncthreads();
      }

      float bv[4];
#pragma unroll
      for (int ni = 0; ni < 4; ++ni) bv[ni] = biasp[wc * 64 + ni * 16 + lr];

      if (isProj) {
        int e0 = sub * 128;
        uint16_t* opack = lA;          // 16 KB [64][128]
#pragma unroll
        for (int chunk = 0; chunk < 4; ++chunk) {
          if (wr == chunk) {
#pragma unroll
            for (int mi = 0; mi < 4; ++mi)
#pragma unroll
              for (int ni = 0; ni < 4; ++ni)
#pragma unroll
                for (int r = 0; r < 4; ++r)
                  opack[(mi * 16 + lg * 4 + r) * 128 + wc * 64 + ni * 16 + lr]
                    = f2b(acc[mi][ni][r] + bv[ni]);
          }
          __syncthreads();
          const unsigned long long* op = (const unsigned long long*)opack;
#pragma unroll
          for (int j = 0; j < 4; ++j) {
            int g = j * 512 + tid;           // 2048 u64 = 64 rows x 32
            int row = g >> 5, seg = g & 31;
            unsigned long long* od =
                (unsigned long long*)(outAll + ((size_t)(t0 + chunk) * B_ + row) * 1024 + e0) + seg;
            __hip_atomic_store(od, op[g], __ATOMIC_RELAXED, __HIP_MEMORY_SCOPE_AGENT);
          }
          __syncthreads();
        }
        asm volatile("s_waitcnt vmcnt(0)" ::: "memory");
        __syncthreads();
        if (tid == 0)
          __hip_atomic_fetch_add(&projDone[tg], 1u, __ATOMIC_RELAXED, __HIP_MEMORY_SCOPE_AGENT);
      } else {
        int nc = sub - 8;
#pragma unroll
        for (int mi = 0; mi < 4; ++mi) {
#pragma unroll
          for (int r = 0; r < 4; ++r) {
            float mx = -1e30f;
#pragma unroll
            for (int ni = 0; ni < 4; ++ni) { acc[mi][ni][r] += bv[ni]; mx = fmaxf(mx, acc[mi][ni][r]); }
#pragma unroll
            for (int d = 1; d < 16; d <<= 1) mx = fmaxf(mx, __shfl_xor(mx, d, 64));
            float s = 0.f;
#pragma unroll
            for (int ni = 0; ni < 4; ++ni) s += expf(acc[mi][ni][r] - mx);
#pragma unroll
            for (int d = 1; d < 16; d <<= 1) s += __shfl_xor(s, d, 64);
            if (lr == 0) cm[wc * 256 + wr * 64 + mi * 16 + lg * 4 + r] = make_float2(mx, s);
          }
        }
        __syncthreads();
        if (tid < 256) {
          float2 p0 = cm[tid], p1 = cm[256 + tid];
          float M = fmaxf(p0.x, p1.x);
          float S = p0.y * expf(p0.x - M) + p1.y * expf(p1.x - M);
          part[(size_t)nc * MROWS + (size_t)t0 * B_ + tid] = make_float2(M, S);
        }
      }
    }
  }
}

// ---------------- target logits ----------------
__global__ __launch_bounds__(256) void k_tgt(
    const uint16_t* __restrict__ outAll, const uint16_t* __restrict__ embB,
    const float* __restrict__ bd, const int* __restrict__ data, float* __restrict__ tgt)
{
  int w = threadIdx.x >> 6, l = threadIdx.x & 63;
  int row = blockIdx.x * 4 + w;
  int t = row >> 6, b = row & 63;
  int ty = data[(t + 1) * B_ + b];
  const uint16_t* a = outAll + (size_t)row * E_;
  const uint16_t* e = embB + (size_t)ty * E_;
  float s = 0.f;
#pragma unroll
  for (int i0 = 0; i0 < 2; ++i0) {
    int i = (l + i0 * 64) * 8;
    bf16x8 av = *(const bf16x8*)(a + i);
    bf16x8 ev = *(const bf16x8*)(e + i);
#pragma unroll
    for (int j = 0; j < 8; ++j) s += (float)av[j] * (float)ev[j];
  }
#pragma unroll
  for (int d = 1; d < 64; d <<= 1) s += __shfl_xor(s, d, 64);
  if (l == 0) tgt[row] = s + bd[ty];
}

// ---------------- LSE over 250 chunks + NLL per row ----------------
__global__ __launch_bounds__(256) void k_lse(
    const float2* __restrict__ part, const float* __restrict__ tgt,
    const float* __restrict__ mask, float* __restrict__ rowNll)
{
  int w = threadIdx.x >> 6, l = threadIdx.x & 63;
  int row = blockIdx.x * 4 + w;
  float m = -1e30f, s = 0.f;
  for (int cc = l; cc < NCB_; cc += 64) {
    float2 v = part[(size_t)cc * MROWS + row];
    float M = fmaxf(m, v.x);
    s = s * expf(m - M) + v.y * expf(v.x - M);
    m = M;
  }
#pragma unroll
  for (int d = 1; d < 64; d <<= 1) {
    float om = __shfl_xor(m, d, 64);
    float os = __shfl_xor(s, d, 64);
    float M = fmaxf(m, om);
    s = s * expf(m - M) + os * expf(om - M);
    m = M;
  }
  if (l == 0) {
    int t = row >> 6, b = row & 63;
    float nll = (m + logf(s)) - tgt[row];
    rowNll[row] = nll * mask[(t + 1) * B_ + b];
  }
}

__global__ void k_final2(const float* __restrict__ rowNll, float* __restrict__ out) {
  __shared__ float red[256];
  float s = 0.f;
  for (int i = threadIdx.x; i < MROWS; i += 256) s += rowNll[i];
  red[threadIdx.x] = s;
  __syncthreads();
  for (int st = 128; st > 0; st >>= 1) {
    if ((int)threadIdx.x < st) red[threadIdx.x] += red[threadIdx.x + st];
    __syncthreads();
  }
  if (threadIdx.x == 0) out[0] = red[0] / (float)(B_ * B_);
}

// ---------------- host ----------------
extern "C" void kernel_launch(void* const* d_in, const int* in_sizes, int n_in,
                              void* d_out, int out_size, void* d_ws, size_t ws_size,
                              hipStream_t stream)
{
  const int*   data = (const int*)  d_in[0];
  const float* mask = (const float*)d_in[1];
  const float* emb  = (const float*)d_in[2];
  const float* W_ih = (const float*)d_in[3];
  const float* W_hh = (const float*)d_in[4];
  const float* bias = (const float*)d_in[5];
  const float* Wr   = (const float*)d_in[6];
  const float* br   = (const float*)d_in[7];
  const float* bd   = (const float*)d_in[8];
  (void)in_sizes; (void)n_in; (void)out_size; (void)ws_size;

  char* ws = (char*)d_ws;
  size_t off = 0;
  auto alloc = [&](size_t bytes) -> char* {
    char* p = ws + off;
    off += (bytes + 255) & ~(size_t)255;
    return p;
  };
  uint16_t* embB   = (uint16_t*)alloc((size_t)V_ * E_ * 2);            // 65.5 MB
  uint16_t* Wcat   = (uint16_t*)alloc((size_t)4 * H_ * 2048 * 2);      // 16.8 MB
  uint16_t* WrB    = (uint16_t*)alloc((size_t)E_ * H_ * 2);            // 2.1 MB
  uint16_t* hAll   = (uint16_t*)alloc((size_t)(T_ + 1) * B_ * H_ * 2); // 16.9 MB
  uint16_t* xAll   = (uint16_t*)alloc((size_t)MROWS * 4096 * 2);       // 67.1 MB
  uint16_t* outAll = (uint16_t*)alloc((size_t)MROWS * E_ * 2);         // 16.8 MB
  float2*   part   = (float2*)  alloc((size_t)NCB_ * MROWS * 8);       // 16.4 MB
  float*    tgt    = (float*)   alloc((size_t)MROWS * 4);
  float*    rowNll = (float*)   alloc((size_t)MROWS * 4);
  uint32_t* syncb  = (uint32_t*)alloc(4096);
  uint32_t* flags    = syncb;          // 64 dwords
  uint32_t* projDone = syncb + 128;    // 32 dwords (per tg)
  uint32_t* workCtr  = syncb + 512;    // 1 dword
  uint32_t* minStep  = syncb + 576;    // 1 dword (own line)

  // one-time conversions
  k_cvt <<<2048, 256, 0, stream>>>(emb, embB, V_ * E_ / 4);
  k_cvt <<<256,  256, 0, stream>>>(Wr, WrB, E_ * H_ / 4);
  k_tcvt<<<dim3(4 * H_ / 32, E_ / 32), dim3(32, 8), 0, stream>>>(W_ih, Wcat, E_, 4 * H_, 2048, 0);
  k_tcvt<<<dim3(4 * H_ / 32, H_ / 32), dim3(32, 8), 0, stream>>>(W_hh, Wcat, H_, 4 * H_, 2048, 1024);
  k_zero<<<32, 256, 0, stream>>>((uint4*)hAll, B_ * H_ * 2 / 16);
  k_zero<<<1, 256, 0, stream>>>((uint4*)syncb, 4096 / 16);

  // xW = emb[x] @ W_ih + b for all (t,b)
  k_xw<<<dim3(MROWS / 128, 4096 / 128), 256, 0, stream>>>(data, embB, Wcat, bias, xAll);

  // fused recurrence + projection + logits (producer/consumer, minStep relay)
  k_mega<<<256, 512, 0, stream>>>(xAll, Wcat, mask, hAll, flags,
                                  embB, WrB, br, bd, outAll, part,
                                  projDone, minStep, workCtr);

  k_tgt   <<<MROWS / 4, 256, 0, stream>>>(outAll, embB, bd, data, tgt);
  k_lse   <<<MROWS / 4, 256, 0, stream>>>(part, tgt, mask, rowNll);
  k_final2<<<1, 256, 0, stream>>>(rowNll, (float*)d_out);
}